// Round 6
// baseline (103.940 us; speedup 1.0000x reference)
//
#include <hip/hip_runtime.h>

#define BATCH 2
#define H 512
#define W 512
#define CS 21
#define CI 3
#define P 128                   // pixels per block (x)
#define R 8                     // output rows per block (vertical run)
#define TPB 256
#define GROWS (R + 2)           // 10 tap rows
#define GSL (P + 2)             // 130 guide slots incl. halo
#define GSZ (GROWS * GSL * CI)  // 3900 guide floats
#define NSETS (R * P)           // 1024 weight sets
#define SWF (NSETS * 12)        // 12288 floats = 49152 B union LDS

typedef float f32x4 __attribute__((ext_vector_type(4)));

__device__ __forceinline__ void fma4(float4& a, const float4 v, const float w) {
    a.x = fmaf(v.x, w, a.x);
    a.y = fmaf(v.y, w, a.y);
    a.z = fmaf(v.z, w, a.z);
    a.w = fmaf(v.w, w, a.w);
}

// out is never re-read: nt store avoids L2 write-allocate evicting src halo.
__device__ __forceinline__ void nt_store4(float* p, const float4 v) {
    __builtin_nontemporal_store(*(const f32x4*)&v, (f32x4*)p);
}

// Load the 3 x-taps of one src row into a float4[3].
#define LOAD3(dst, rr, om, oc, op)                              \
    (dst)[0] = *(const float4*)(srow[rr] + (om));               \
    (dst)[1] = *(const float4*)(srow[rr] + (oc));               \
    (dst)[2] = *(const float4*)(srow[rr] + (op));

// Row selector: rows 0..5 live in va[6][3], rows 6..9 in vb[4][3].
#define VA_I(r) ((r) < 6 ? (r) : 5)
#define VB_I(r) ((r) < 6 ? 0 : (r) - 6)
#define VR(va, vb, r, k) ((r) < 6 ? (va)[VA_I(r)][(k)] : (vb)[VB_I(r)][(k)])

// 8-row vertical run: same fma ordering as R2 (bit-identical output).
#define COMPUTE8(va, vb, px, oc)                                             \
    {                                                                        \
        _Pragma("unroll")                                                    \
        for (int j = 0; j < R; ++j) {                                        \
            const float* wd = &s_u[((j << 7) + (px)) * 12];                  \
            float4 wA = *(const float4*)(wd + 0);                            \
            float4 wB = *(const float4*)(wd + 4);                            \
            float  w8 = wd[8];                                               \
            float4 acc = {0.f, 0.f, 0.f, 0.f};                               \
            fma4(acc, VR(va, vb, j + 0, 0), wA.x);                           \
            fma4(acc, VR(va, vb, j + 0, 1), wA.y);                           \
            fma4(acc, VR(va, vb, j + 0, 2), wA.z);                           \
            fma4(acc, VR(va, vb, j + 1, 0), wA.w);                           \
            fma4(acc, VR(va, vb, j + 1, 1), wB.x);                           \
            fma4(acc, VR(va, vb, j + 1, 2), wB.y);                           \
            fma4(acc, VR(va, vb, j + 2, 0), wB.z);                           \
            fma4(acc, VR(va, vb, j + 2, 1), wB.w);                           \
            fma4(acc, VR(va, vb, j + 2, 2), w8);                             \
            nt_store4(ob + (size_t)j * rs + (oc), acc);                      \
        }                                                                    \
    }

// R2 (best: P=128/R=8/TPB=256) + LDS union: guide tile and weight table share
// one 48KB region (guide is dead once weights are in registers; a barrier
// separates last guide read from first weight write). 64.75->48 KB/block =
// 3 blocks/CU, 12 waves/CU at the proven tile size. R4 spill lesson: va1
// pre-weight prefetch dropped so peak live regs (~130) stay under the
// launch_bounds(256,3) cap of 168; inter-block overlap replaces it.
__global__ __launch_bounds__(TPB, 3) void jbu_kernel(
    const float* __restrict__ src, const float* __restrict__ im,
    float* __restrict__ out)
{
    __shared__ __align__(16) float s_u[SWF];   // union: guide, then weights

    const int t = threadIdx.x;

    // XCD swizzle: XCD (f&7) owns a contiguous 64-output-row band.
    const int f      = blockIdx.x;        // 0..511
    const int xcd    = f & 7;
    const int g      = f >> 3;            // 0..63
    const int rowgrp = (xcd << 3) | (g & 7);    // 0..63
    const int rem    = g >> 3;            // 0..7
    const int x0     = (rem & 3) << 7;    // segment * 128
    const int b      = rem >> 2;
    const int y0     = rowgrp << 3;       // output rows y0..y0+7

    const size_t rs = (size_t)W * CS;
    const float* sb = src + (size_t)b * H * rs;
    const float* srow[GROWS];             // wave-uniform -> SGPRs
    #pragma unroll
    for (int rr = 0; rr < GROWS; ++rr) {
        int v = y0 - 1 + rr;
        int tyr = (v < 0) ? 1 : ((v >= H) ? 2 * H - 2 - v : v);
        srow[rr] = sb + (size_t)tyr * rs + (size_t)x0 * CS;
    }

    // ---- it=0 addressing + full 6-row prefetch (rows 0..5) ----
    const int px0   = t / 6;              // 0..42
    const int q0    = t - px0 * 6;
    const int coff0 = (q0 == 5) ? 17 : (q0 << 2);
    const int x_    = x0 + px0;
    const int xm_   = (x_ == 0)     ? 1     : x_ - 1;
    const int xp_   = (x_ == W - 1) ? W - 2 : x_ + 1;
    const int om0   = (xm_ - x0) * CS + coff0;   // may be negative: valid in-row
    const int oc0   = px0 * CS + coff0;
    const int op0   = (xp_ - x0) * CS + coff0;

    float4 va0[6][3];
    #pragma unroll
    for (int rr = 0; rr < 6; ++rr) { LOAD3(va0[rr], rr, om0, oc0, op0) }

    // ---- stage guide tile into s_u[0..GSZ): async global->LDS ----
    const float* imb = im + (size_t)b * (H * W * CI);
    for (int i = t; i < GSZ; i += TPB) {
        int rr   = i / (GSL * CI);
        int remi = i - rr * (GSL * CI);
        int slot = remi / CI;
        int ch   = remi - slot * CI;
        int gx   = x0 + slot - 1;
        gx = (gx < 0) ? 1 : ((gx >= W) ? W - 2 : gx);
        int vv = y0 - 1 + rr;
        int tyr = (vv < 0) ? 1 : ((vv >= H) ? 2 * H - 2 - vv : vv);
        const float* gsrc = imb + ((size_t)tyr * W + gx) * CI + ch;
        __builtin_amdgcn_global_load_lds(
            (const __attribute__((address_space(1))) void*)gsrc,
            (__attribute__((address_space(3))) void*)(s_u + i), 4, 0, 0);
    }
    __syncthreads();

    // ---- weights into REGISTERS (guide still live in s_u) ----
    // NSETS=1024 sets, 4 per thread. Same math/order as R2.
    float wreg[4][9];
    {
        const float w1k[9] = {0.36787944f, 0.60653066f, 0.36787944f,
                              0.60653066f, 1.0f,        0.60653066f,
                              0.36787944f, 0.60653066f, 0.36787944f};
        #pragma unroll
        for (int ii = 0; ii < 4; ++ii) {
            int idx = ii * TPB + t;       // 0..1023
            int r   = idx >> 7;           // 0..7   (idx / P)
            int px  = idx & (P - 1);
            int cb  = ((r + 1) * GSL + px + 1) * CI;
            float c0 = s_u[cb + 0], c1 = s_u[cb + 1], c2 = s_u[cb + 2];
            float wv[9];
            float den = 0.f;
            #pragma unroll
            for (int k = 0; k < 9; ++k) {
                int dy = k / 3, dx = k % 3;
                int ib = ((r + dy) * GSL + px + dx) * CI;
                float d0 = s_u[ib + 0] - c0;
                float d1 = s_u[ib + 1] - c1;
                float d2 = s_u[ib + 2] - c2;
                float w = __expf(-8.0f * (d0 * d0 + d1 * d1 + d2 * d2)) * w1k[k];
                wv[k] = w;
                den += w;
            }
            float inv = 1.0f / den;
            #pragma unroll
            for (int k = 0; k < 9; ++k) wreg[ii][k] = wv[k] * inv;
        }
    }
    __syncthreads();   // all guide reads done; s_u may now be overwritten

    // ---- write weight table into the SAME LDS region ----
    #pragma unroll
    for (int ii = 0; ii < 4; ++ii) {
        int idx = ii * TPB + t;
        float* wd = &s_u[idx * 12];
        *(float4*)(wd + 0) = make_float4(wreg[ii][0], wreg[ii][1], wreg[ii][2], wreg[ii][3]);
        *(float4*)(wd + 4) = make_float4(wreg[ii][4], wreg[ii][5], wreg[ii][6], wreg[ii][7]);
        wd[8] = wreg[ii][8];
    }
    __syncthreads();

    // ---- phase 2: 8-row vertical runs, taps from global, weights from LDS ----
    float* ob = out + ((size_t)(b * H + y0)) * rs + (size_t)x0 * CS;

    // it = 0: va0 ready; fetch rows 6..9 (hidden under early-j fmas)
    {
        float4 vb0[4][3];
        #pragma unroll
        for (int rr = 0; rr < 4; ++rr) { LOAD3(vb0[rr], rr + 6, om0, oc0, op0) }
        COMPUTE8(va0, vb0, px0, oc0)
    }

    // it = 1,2: full load (no barrier above: loads overlap prior compute)
    #pragma unroll
    for (int it = 1; it < (P * 6) / TPB; ++it) {
        const int item = it * TPB + t;
        const int px   = item / 6;
        const int q    = item - px * 6;
        const int coff = (q == 5) ? 17 : (q << 2);
        const int x    = x0 + px;
        const int xm   = (x == 0)     ? 1     : x - 1;
        const int xp   = (x == W - 1) ? W - 2 : x + 1;
        const int om   = (xm - x0) * CS + coff;
        const int oc   = px * CS + coff;
        const int op   = (xp - x0) * CS + coff;

        float4 va[6][3];
        #pragma unroll
        for (int rr = 0; rr < 6; ++rr) { LOAD3(va[rr], rr, om, oc, op) }
        float4 vb[4][3];
        #pragma unroll
        for (int rr = 0; rr < 4; ++rr) { LOAD3(vb[rr], rr + 6, om, oc, op) }
        COMPUTE8(va, vb, px, oc)
    }
}

extern "C" void kernel_launch(void* const* d_in, const int* in_sizes, int n_in,
                              void* d_out, int out_size, void* d_ws, size_t ws_size,
                              hipStream_t stream) {
    const float* src = (const float*)d_in[0];
    const float* im  = (const float*)d_in[1];
    float* out = (float*)d_out;
    dim3 grid((W / P) * (H / R) * BATCH, 1, 1);   // 512 blocks = 3/CU capable
    jbu_kernel<<<grid, TPB, 0, stream>>>(src, im, out);
}

// Round 7
// 102.708 us; speedup vs baseline: 1.0120x; 1.0120x over previous
//
#include <hip/hip_runtime.h>

#define BATCH 2
#define H 512
#define W 512
#define CS 21
#define CI 3
#define P 64                    // pixels per block (x)
#define R 8                     // output rows per block (vertical run)
#define TPB 256
#define GROWS (R + 2)           // 10 tap rows
#define GSL (P + 2)             // 66 guide slots incl. halo
#define GSZ (GROWS * GSL * CI)  // 1980 guide floats
#define NSETS (R * P)           // 512 weight sets
#define NITEMS (P * 6)          // 384 phase-2 items

typedef float f32x4 __attribute__((ext_vector_type(4)));

__device__ __forceinline__ void fma4(float4& a, const float4 v, const float w) {
    a.x = fmaf(v.x, w, a.x);
    a.y = fmaf(v.y, w, a.y);
    a.z = fmaf(v.z, w, a.z);
    a.w = fmaf(v.w, w, a.w);
}

// out is never re-read: nt store avoids L2 write-allocate evicting src halo.
__device__ __forceinline__ void nt_store4(float* p, const float4 v) {
    __builtin_nontemporal_store(*(const f32x4*)&v, (f32x4*)p);
}

// Load the 3 x-taps of one src row into a float4[3].
#define LOAD3(dst, rr, om, oc, op)                              \
    (dst)[0] = *(const float4*)(srow[rr] + (om));               \
    (dst)[1] = *(const float4*)(srow[rr] + (oc));               \
    (dst)[2] = *(const float4*)(srow[rr] + (op));

// Row selector: rows 0..5 live in va[6][3], rows 6..9 in vb[4][3].
#define VA_I(r) ((r) < 6 ? (r) : 5)
#define VB_I(r) ((r) < 6 ? 0 : (r) - 6)
#define VR(va, vb, r, k) ((r) < 6 ? (va)[VA_I(r)][(k)] : (vb)[VB_I(r)][(k)])

// 8-row vertical run: same fma ordering as R1 (bit-identical output).
// Weight tables split (f4-aligned, no 12-float padding).
#define COMPUTE8(va, vb, px, oc)                                             \
    {                                                                        \
        _Pragma("unroll")                                                    \
        for (int j = 0; j < R; ++j) {                                        \
            const int s = (j << 6) + (px);                                   \
            float4 wA = *(const float4*)&s_wA[s * 4];                        \
            float4 wB = *(const float4*)&s_wB[s * 4];                        \
            float  w8 = s_w8[s];                                             \
            float4 acc = {0.f, 0.f, 0.f, 0.f};                               \
            fma4(acc, VR(va, vb, j + 0, 0), wA.x);                           \
            fma4(acc, VR(va, vb, j + 0, 1), wA.y);                           \
            fma4(acc, VR(va, vb, j + 0, 2), wA.z);                           \
            fma4(acc, VR(va, vb, j + 1, 0), wA.w);                           \
            fma4(acc, VR(va, vb, j + 1, 1), wB.x);                           \
            fma4(acc, VR(va, vb, j + 1, 2), wB.y);                           \
            fma4(acc, VR(va, vb, j + 2, 0), wB.z);                           \
            fma4(acc, VR(va, vb, j + 2, 1), wB.w);                           \
            fma4(acc, VR(va, vb, j + 2, 2), w8);                             \
            nt_store4(ob + (size_t)j * rs + (oc), acc);                      \
        }                                                                    \
    }

// Clean test of inter-block phase overlap (R6 lesson: 512-block grids cap at
// 2 blocks/CU no matter how small LDS is). P=64 -> 1024 blocks; 26.3 KB LDS
// (split f4-aligned weight tables + separate guide region = R1's hazard-free
// direct-to-LDS weight write, 2 barriers only); launch_bounds(256,3) -> 3
// blocks/CU resident, grid supplies 4: one block's stage/weight head hides
// under neighbors' phase-2 streaming. No va1 pre-barrier prefetch (R4 spill
// lesson; peak live ~112 regs < 168 cap).
__global__ __launch_bounds__(TPB, 3) void jbu_kernel(
    const float* __restrict__ src, const float* __restrict__ im,
    float* __restrict__ out)
{
    __shared__ float s_g[GSZ];                         // 7,920 B guide tile
    __shared__ __align__(16) float s_wA[NSETS * 4];    // 8,192 B
    __shared__ __align__(16) float s_wB[NSETS * 4];    // 8,192 B
    __shared__ float s_w8[NSETS];                      // 2,048 B

    const int t = threadIdx.x;

    // XCD swizzle: XCD (f&7) owns a contiguous 64-output-row band.
    const int f      = blockIdx.x;        // 0..1023
    const int xcd    = f & 7;
    const int g      = f >> 3;            // 0..127
    const int rowgrp = (xcd << 3) | (g & 7);    // 0..63
    const int rem    = g >> 3;            // 0..15
    const int x0     = (rem & 7) << 6;    // 8 x-segments * 64 px
    const int b      = rem >> 3;          // batch
    const int y0     = rowgrp << 3;       // output rows y0..y0+7

    const size_t rs = (size_t)W * CS;
    const float* sb = src + (size_t)b * H * rs;
    const float* srow[GROWS];             // wave-uniform -> SGPRs
    #pragma unroll
    for (int rr = 0; rr < GROWS; ++rr) {
        int v = y0 - 1 + rr;
        int tyr = (v < 0) ? 1 : ((v >= H) ? 2 * H - 2 - v : v);
        srow[rr] = sb + (size_t)tyr * rs + (size_t)x0 * CS;
    }

    // ---- it=0 addressing + 6-row prefetch (rows 0..5) ----
    const int px0   = t / 6;              // 0..42
    const int q0    = t - px0 * 6;
    const int coff0 = (q0 == 5) ? 17 : (q0 << 2);
    const int x_    = x0 + px0;
    const int xm_   = (x_ == 0)     ? 1     : x_ - 1;
    const int xp_   = (x_ == W - 1) ? W - 2 : x_ + 1;
    const int om0   = (xm_ - x0) * CS + coff0;   // may be negative: valid in-row
    const int oc0   = px0 * CS + coff0;
    const int op0   = (xp_ - x0) * CS + coff0;

    float4 va0[6][3];
    #pragma unroll
    for (int rr = 0; rr < 6; ++rr) { LOAD3(va0[rr], rr, om0, oc0, op0) }

    // ---- stage guide tile: async global->LDS (linear dest = base + lane*4) ----
    const float* imb = im + (size_t)b * (H * W * CI);
    for (int i = t; i < GSZ; i += TPB) {
        int rr   = i / (GSL * CI);
        int remi = i - rr * (GSL * CI);
        int slot = remi / CI;
        int ch   = remi - slot * CI;
        int gx   = x0 + slot - 1;
        gx = (gx < 0) ? 1 : ((gx >= W) ? W - 2 : gx);
        int vv = y0 - 1 + rr;
        int tyr = (vv < 0) ? 1 : ((vv >= H) ? 2 * H - 2 - vv : vv);
        const float* gsrc = imb + ((size_t)tyr * W + gx) * CI + ch;
        __builtin_amdgcn_global_load_lds(
            (const __attribute__((address_space(1))) void*)gsrc,
            (__attribute__((address_space(3))) void*)(s_g + i), 4, 0, 0);
    }
    __syncthreads();

    // ---- weights: 512 sets, 2 per thread, direct to split LDS tables ----
    {
        const float w1k[9] = {0.36787944f, 0.60653066f, 0.36787944f,
                              0.60653066f, 1.0f,        0.60653066f,
                              0.36787944f, 0.60653066f, 0.36787944f};
        #pragma unroll
        for (int ii = 0; ii < NSETS / TPB; ++ii) {
            int idx = ii * TPB + t;       // 0..511
            int r   = idx >> 6;           // 0..7   (idx / P)
            int px  = idx & (P - 1);
            int cb  = ((r + 1) * GSL + px + 1) * CI;
            float c0 = s_g[cb + 0], c1 = s_g[cb + 1], c2 = s_g[cb + 2];
            float wv[9];
            float den = 0.f;
            #pragma unroll
            for (int k = 0; k < 9; ++k) {
                int dy = k / 3, dx = k % 3;
                int ib = ((r + dy) * GSL + px + dx) * CI;
                float d0 = s_g[ib + 0] - c0;
                float d1 = s_g[ib + 1] - c1;
                float d2 = s_g[ib + 2] - c2;
                float w = __expf(-8.0f * (d0 * d0 + d1 * d1 + d2 * d2)) * w1k[k];
                wv[k] = w;
                den += w;
            }
            float inv = 1.0f / den;
            *(float4*)&s_wA[idx * 4] = make_float4(wv[0] * inv, wv[1] * inv, wv[2] * inv, wv[3] * inv);
            *(float4*)&s_wB[idx * 4] = make_float4(wv[4] * inv, wv[5] * inv, wv[6] * inv, wv[7] * inv);
            s_w8[idx] = wv[8] * inv;
        }
    }
    __syncthreads();

    // ---- phase 2: 8-row vertical runs, taps from global, weights from LDS ----
    float* ob = out + ((size_t)(b * H + y0)) * rs + (size_t)x0 * CS;

    // it = 0: va0 ready; fetch rows 6..9 (hidden under early-j fmas)
    {
        float4 vb0[4][3];
        #pragma unroll
        for (int rr = 0; rr < 4; ++rr) { LOAD3(vb0[rr], rr + 6, om0, oc0, op0) }
        COMPUTE8(va0, vb0, px0, oc0)
    }

    // it = 1: items 256..383, threads t<128 only (no barrier above: these
    // loads overlap it0's compute via scheduler)
    if (t < NITEMS - TPB) {
        const int item = TPB + t;         // 256..383
        const int px   = item / 6;        // 42..63
        const int q    = item - px * 6;
        const int coff = (q == 5) ? 17 : (q << 2);
        const int x    = x0 + px;
        const int xm   = (x == 0)     ? 1     : x - 1;
        const int xp   = (x == W - 1) ? W - 2 : x + 1;
        const int om   = (xm - x0) * CS + coff;
        const int oc   = px * CS + coff;
        const int op   = (xp - x0) * CS + coff;

        float4 va[6][3];
        #pragma unroll
        for (int rr = 0; rr < 6; ++rr) { LOAD3(va[rr], rr, om, oc, op) }
        float4 vb[4][3];
        #pragma unroll
        for (int rr = 0; rr < 4; ++rr) { LOAD3(vb[rr], rr + 6, om, oc, op) }
        COMPUTE8(va, vb, px, oc)
    }
}

extern "C" void kernel_launch(void* const* d_in, const int* in_sizes, int n_in,
                              void* d_out, int out_size, void* d_ws, size_t ws_size,
                              hipStream_t stream) {
    const float* src = (const float*)d_in[0];
    const float* im  = (const float*)d_in[1];
    float* out = (float*)d_out;
    dim3 grid((W / P) * (H / R) * BATCH, 1, 1);   // 1024 blocks, 3/CU resident
    jbu_kernel<<<grid, TPB, 0, stream>>>(src, im, out);
}